// Round 14
// baseline (118.235 us; speedup 1.0000x reference)
//
#include <hip/hip_runtime.h>
#include <math.h>

#define BATCH 32
#define LSEQ  2048
#define DIM   1024
#define DIM2  2048

constexpr float EPSF = 1e-5f;

constexpr int CHUNKS = 64;                    // max k1 chunks per batch (32 rows each)

constexpr int KSEG1 = 32;
constexpr int NSEG1 = DIM / KSEG1;            // 32 k-segments for matmul 1
constexpr int KSEG2 = 32;
constexpr int NSEG2 = DIM2 / KSEG2;           // 64 k-segments for matmul 2

constexpr int K4_ROWS = 4;                    // rows per k4 block (R12-proven)

typedef float f4v __attribute__((ext_vector_type(4)));

// ---------------------------------------------------------------------------
// K0: per-batch compaction of context-row indices from target_mask (R12 exact).
// ---------------------------------------------------------------------------
__global__ __launch_bounds__(256) void k0_compact(const int* __restrict__ m32,
                                                  int* __restrict__ rowlist,
                                                  int* __restrict__ cnt,
                                                  int* __restrict__ ntgt) {
    const int b    = blockIdx.x;
    const int t    = threadIdx.x;
    const int wave = t >> 6, lane = t & 63;

    const int probe = m32[(size_t)b * 2048 + 8 * t + 1];
    __shared__ unsigned long long pbw[4];
    const unsigned long long pb = __ballot(probe != 0);
    if (lane == 0) pbw[wave] = pb;
    __syncthreads();
    const int stride = ((pbw[0] | pbw[1] | pbw[2] | pbw[3]) != 0ull) ? 1 : 2;

    const int base = t * 8;
    int f[8];
    int ls = 0;
    #pragma unroll
    for (int k = 0; k < 8; ++k) {
        f[k] = (m32[((size_t)b * 2048 + base + k) * (size_t)stride] == 0) ? 1 : 0;
        ls += f[k];
    }

    int v = ls;
    #pragma unroll
    for (int o = 1; o < 64; o <<= 1) {
        const int u = __shfl_up(v, o, 64);
        if (lane >= o) v += u;
    }
    __shared__ int wsum[4];
    if (lane == 63) wsum[wave] = v;
    __syncthreads();
    int wbase = 0;
    for (int w = 0; w < wave; ++w) wbase += wsum[w];
    const int excl = wbase + v - ls;

    int c = 0;
    #pragma unroll
    for (int k = 0; k < 8; ++k) {
        if (f[k]) { rowlist[(size_t)b * 2048 + excl + c] = base + k; ++c; }
    }
    if (t == 0) {
        const int tot = wsum[0] + wsum[1] + wsum[2] + wsum[3];
        cnt[b]  = tot;
        ntgt[b] = LSEQ - tot;
    }
}

// ---------------------------------------------------------------------------
// K1: gather-sum over context rows only (R12 exact; probe-verified ~18 us).
// ---------------------------------------------------------------------------
__global__ __launch_bounds__(256) void k1_gather(const float* __restrict__ x,
                                                 const int* __restrict__ rowlist,
                                                 const int* __restrict__ cnt,
                                                 float* __restrict__ psum) {
    const int chunk = blockIdx.x;
    const int b     = blockIdx.y;
    const int t     = threadIdx.x;

    const int cntb = cnt[b];
    const int nch  = (cntb + 31) >> 5;
    if (chunk >= nch) return;
    const int rbeg = chunk * 32;
    const int rcnt = min(32, cntb - rbeg);

    __shared__ int sidx[32];
    if (t < rcnt) sidx[t] = rowlist[(size_t)b * 2048 + rbeg + t];
    __syncthreads();

    const float* xb = x + (size_t)b * LSEQ * DIM + t * 4;
    float4 acc = make_float4(0.f, 0.f, 0.f, 0.f);

    if (rcnt == 32) {
        #pragma unroll 8
        for (int r = 0; r < 32; ++r) {
            const float4 v = *(const float4*)(xb + (size_t)sidx[r] * DIM);
            acc.x += v.x; acc.y += v.y; acc.z += v.z; acc.w += v.w;
        }
    } else {
        for (int r = 0; r < rcnt; ++r) {
            const float4 v = *(const float4*)(xb + (size_t)sidx[r] * DIM);
            acc.x += v.x; acc.y += v.y; acc.z += v.z; acc.w += v.w;
        }
    }

    *(float4*)(psum + ((size_t)b * CHUNKS + chunk) * DIM + t * 4) = acc;
}

// ---------------------------------------------------------------------------
// K2: mean from psum chunks (R12 exact).
// ---------------------------------------------------------------------------
__global__ __launch_bounds__(256) void k2_mean(const float* __restrict__ psum,
                                               const int* __restrict__ cnt,
                                               float* __restrict__ mean) {
    const int b = blockIdx.x;
    const int t = threadIdx.x;
    const int cntb = cnt[b];
    const int nch  = (cntb + 31) >> 5;

    float4 s = make_float4(0.f, 0.f, 0.f, 0.f);
    for (int c = 0; c < nch; ++c) {
        const float4 v = *(const float4*)(psum + ((size_t)b * CHUNKS + c) * DIM + t * 4);
        s.x += v.x; s.y += v.y; s.z += v.z; s.w += v.w;
    }
    const float denom = (float)(cntb > 1 ? cntb : 1);
    float4 m4;
    m4.x = s.x / denom; m4.y = s.y / denom; m4.z = s.z / denom; m4.w = s.w / denom;
    *(float4*)(mean + (size_t)b * DIM + t * 4) = m4;
}

// ---------------------------------------------------------------------------
// K3a: p1[ks][b][j] = mean[b, k-seg] @ W1[k-seg, j] (R12 exact).
// ---------------------------------------------------------------------------
__global__ __launch_bounds__(256) void k3a_h(const float* __restrict__ mean,
                                             const float* __restrict__ W1,
                                             float* __restrict__ p1) {
    const int j  = blockIdx.x * 256 + threadIdx.x;
    const int ks = blockIdx.y;
    const int k0 = ks * KSEG1;

    __shared__ float mlds[BATCH][KSEG1];
    for (int i = threadIdx.x; i < BATCH * KSEG1; i += 256)
        mlds[i >> 5][i & 31] = mean[(size_t)(i >> 5) * DIM + k0 + (i & 31)];
    __syncthreads();

    float acc[BATCH];
    #pragma unroll
    for (int b = 0; b < BATCH; ++b) acc[b] = 0.f;

    #pragma unroll
    for (int k4 = 0; k4 < KSEG1 / 4; ++k4) {
        const float w0 = W1[(size_t)(k0 + 4 * k4 + 0) * DIM2 + j];
        const float w1 = W1[(size_t)(k0 + 4 * k4 + 1) * DIM2 + j];
        const float w2 = W1[(size_t)(k0 + 4 * k4 + 2) * DIM2 + j];
        const float w3 = W1[(size_t)(k0 + 4 * k4 + 3) * DIM2 + j];
        #pragma unroll
        for (int b = 0; b < BATCH; ++b) {
            const float4 m4 = *(const float4*)&mlds[b][k4 * 4];
            acc[b] += m4.x * w0; acc[b] += m4.y * w1;
            acc[b] += m4.z * w2; acc[b] += m4.w * w3;
        }
    }
    #pragma unroll
    for (int b = 0; b < BATCH; ++b)
        p1[((size_t)ks * BATCH + b) * DIM2 + j] = acc[b];
}

__device__ __forceinline__ float gelu_erf(float v) {
    return 0.5f * v * (1.f + erff(v * 0.70710678118654752f));
}

__device__ __forceinline__ float wave_sum(float v) {
    #pragma unroll
    for (int o = 32; o > 0; o >>= 1) v += __shfl_down(v, o, 64);
    return v;
}

// ---------------------------------------------------------------------------
// K3b (float4): h = sum(p1)+b1; gelu(erf); LayerNorm -> hn (R12 exact).
// ---------------------------------------------------------------------------
__global__ __launch_bounds__(256) void k3b_ln(const float* __restrict__ p1,
                                              const float* __restrict__ b1,
                                              const float* __restrict__ gamma,
                                              const float* __restrict__ beta,
                                              float* __restrict__ hn) {
    const int b = blockIdx.x;
    const int t = threadIdx.x;
    const int wave = t >> 6, lane = t & 63;
    __shared__ float red[4];

    float4 g[2];
    float ls = 0.f;
    #pragma unroll
    for (int i = 0; i < 2; ++i) {
        const int j = t * 4 + i * 1024;
        float4 s = *(const float4*)(b1 + j);
        #pragma unroll 8
        for (int ks = 0; ks < NSEG1; ++ks) {
            const float4 v = *(const float4*)(p1 + ((size_t)ks * BATCH + b) * DIM2 + j);
            s.x += v.x; s.y += v.y; s.z += v.z; s.w += v.w;
        }
        g[i].x = gelu_erf(s.x); g[i].y = gelu_erf(s.y);
        g[i].z = gelu_erf(s.z); g[i].w = gelu_erf(s.w);
        ls += g[i].x + g[i].y + g[i].z + g[i].w;
    }

    float w = wave_sum(ls);
    if (lane == 0) red[wave] = w;
    __syncthreads();
    const float mu = (red[0] + red[1] + red[2] + red[3]) * (1.f / (float)DIM2);
    __syncthreads();

    float lv = 0.f;
    #pragma unroll
    for (int i = 0; i < 2; ++i) {
        float d;
        d = g[i].x - mu; lv += d * d;
        d = g[i].y - mu; lv += d * d;
        d = g[i].z - mu; lv += d * d;
        d = g[i].w - mu; lv += d * d;
    }
    w = wave_sum(lv);
    if (lane == 0) red[wave] = w;
    __syncthreads();
    const float var = (red[0] + red[1] + red[2] + red[3]) * (1.f / (float)DIM2);
    const float rs = rsqrtf(var + EPSF);

    #pragma unroll
    for (int i = 0; i < 2; ++i) {
        const int j = t * 4 + i * 1024;
        const float4 ga = *(const float4*)(gamma + j);
        const float4 be = *(const float4*)(beta + j);
        float4 o;
        o.x = (g[i].x - mu) * rs * ga.x + be.x;
        o.y = (g[i].y - mu) * rs * ga.y + be.y;
        o.z = (g[i].z - mu) * rs * ga.z + be.z;
        o.w = (g[i].w - mu) * rs * ga.w + be.w;
        *(float4*)(hn + (size_t)b * DIM2 + j) = o;
    }
}

// ---------------------------------------------------------------------------
// K3c: p2[ks][b][j] = hn[b, k-seg] @ W2[k-seg, j] (R12 exact).
// ---------------------------------------------------------------------------
__global__ __launch_bounds__(256) void k3c_o(const float* __restrict__ hn,
                                             const float* __restrict__ W2,
                                             float* __restrict__ p2) {
    const int j  = blockIdx.x * 256 + threadIdx.x;
    const int ks = blockIdx.y;
    const int k0 = ks * KSEG2;

    __shared__ float hl[BATCH][KSEG2];
    for (int i = threadIdx.x; i < BATCH * KSEG2; i += 256)
        hl[i >> 5][i & 31] = hn[(size_t)(i >> 5) * DIM2 + k0 + (i & 31)];
    __syncthreads();

    float acc[BATCH];
    #pragma unroll
    for (int b = 0; b < BATCH; ++b) acc[b] = 0.f;

    #pragma unroll
    for (int k4 = 0; k4 < KSEG2 / 4; ++k4) {
        const float w0 = W2[(size_t)(k0 + 4 * k4 + 0) * DIM + j];
        const float w1 = W2[(size_t)(k0 + 4 * k4 + 1) * DIM + j];
        const float w2 = W2[(size_t)(k0 + 4 * k4 + 2) * DIM + j];
        const float w3 = W2[(size_t)(k0 + 4 * k4 + 3) * DIM + j];
        #pragma unroll
        for (int b = 0; b < BATCH; ++b) {
            const float4 h4 = *(const float4*)&hl[b][k4 * 4];
            acc[b] += h4.x * w0; acc[b] += h4.y * w1;
            acc[b] += h4.z * w2; acc[b] += h4.w * w3;
        }
    }
    #pragma unroll
    for (int b = 0; b < BATCH; ++b)
        p2[((size_t)ks * BATCH + b) * DIM + j] = acc[b];
}

// ---------------------------------------------------------------------------
// K3d (float4): pred[b][j] = sum_ks p2[ks][b][j] + b2[j] (R12 exact).
// ---------------------------------------------------------------------------
__global__ __launch_bounds__(256) void k3d_pred(const float* __restrict__ p2,
                                                const float* __restrict__ b2,
                                                float* __restrict__ pred) {
    const int b = blockIdx.x;
    const int j = threadIdx.x * 4;
    float4 s = *(const float4*)(b2 + j);
    #pragma unroll 8
    for (int ks = 0; ks < NSEG2; ++ks) {
        const float4 v = *(const float4*)(p2 + ((size_t)ks * BATCH + b) * DIM + j);
        s.x += v.x; s.y += v.y; s.z += v.z; s.w += v.w;
    }
    *(float4*)(pred + (size_t)b * DIM + j) = s;
}

// ---------------------------------------------------------------------------
// K4: 4 rows per block (R12 shape) — A/B CHANGE: PLAIN stores instead of
// nontemporal. Hypothesis: nt bypasses L2 write-aggregation; the harness's
// plain-store fill hits ~7 TB/s while R11's nt probe pattern ran ~4 TB/s.
// Cost side: out (140 MB) now pollutes L2/L3, may cool x for next replay's k1.
// ---------------------------------------------------------------------------
__global__ __launch_bounds__(256) void k4_scatter(const float* __restrict__ pred,
                                                  const int* __restrict__ ntgt,
                                                  f4v* __restrict__ out,
                                                  int T) {
    const int b  = blockIdx.y;
    const int t0 = blockIdx.x * K4_ROWS;
    const int d4 = threadIdx.x;
    const int n  = ntgt[b];

    const f4v p = ((const f4v*)pred)[b * 256 + d4];
    const f4v z = (f4v)(0.f);

    f4v* o = out + ((size_t)b * T + t0) * 256 + d4;
    #pragma unroll
    for (int r = 0; r < K4_ROWS; ++r) {
        const int tt = t0 + r;
        if (tt >= T) break;                   // block-uniform
        o[(size_t)r * 256] = (tt < n) ? p : z;   // plain store (was nt)
    }
}

// ---------------------------------------------------------------------------
extern "C" void kernel_launch(void* const* d_in, const int* in_sizes, int n_in,
                              void* d_out, int out_size, void* d_ws, size_t ws_size,
                              hipStream_t stream) {
    const float* x     = (const float*)d_in[0];
    const int*   mask  = (const int*)d_in[1];
    const float* W1    = (const float*)d_in[2];
    const float* b1    = (const float*)d_in[3];
    const float* gamma = (const float*)d_in[4];
    const float* beta  = (const float*)d_in[5];
    const float* W2    = (const float*)d_in[6];
    const float* b2    = (const float*)d_in[7];

    char* ws = (char*)d_ws;
    float* psum = (float*)(ws);                                   // 8 MB (alias p2)
    float* p2   = psum;                                           // psum dead after k2
    float* p1   = (float*)(ws + (8u  << 20));                     // 8 MB
    float* mean = (float*)(ws + (16u << 20));                     // 128 KB
    float* hn   = (float*)(ws + (16u << 20) + (128u << 10));      // 256 KB
    float* pred = (float*)(ws + (16u << 20) + (384u << 10));      // 128 KB
    int* rowlist= (int*)  (ws + (17u << 20));                     // 256 KB
    int*   cnt  = rowlist + BATCH * LSEQ;
    int*   ntgt = cnt + 64;

    const int T = out_size / (BATCH * DIM);

    k0_compact<<<BATCH, 256, 0, stream>>>(mask, rowlist, cnt, ntgt);
    k1_gather<<<dim3(CHUNKS, BATCH), 256, 0, stream>>>(x, rowlist, cnt, psum);
    k2_mean  <<<BATCH, 256, 0, stream>>>(psum, cnt, mean);
    k3a_h    <<<dim3(DIM2 / 256, NSEG1), 256, 0, stream>>>(mean, W1, p1);
    k3b_ln   <<<BATCH, 256, 0, stream>>>(p1, b1, gamma, beta, hn);
    k3c_o    <<<dim3(DIM / 256, NSEG2), 256, 0, stream>>>(hn, W2, p2);
    k3d_pred <<<BATCH, 256, 0, stream>>>(p2, b2, pred);
    k4_scatter<<<dim3((T + K4_ROWS - 1) / K4_ROWS, BATCH), 256, 0, stream>>>(pred, ntgt, (f4v*)d_out, T);
}

// Round 15
// 106.187 us; speedup vs baseline: 1.1135x; 1.1135x over previous
//
#include <hip/hip_runtime.h>
#include <math.h>

#define BATCH 32
#define LSEQ  2048
#define DIM   1024
#define DIM2  2048

constexpr float EPSF = 1e-5f;

constexpr int CHUNKS = 64;                    // max k1 chunks per batch (32 rows each)

constexpr int KSEG1 = 32;
constexpr int NSEG1 = DIM / KSEG1;            // 32 k-segments for matmul 1
constexpr int KSEG2 = 32;
constexpr int NSEG2 = DIM2 / KSEG2;           // 64 k-segments for matmul 2

constexpr int K4_ROWS = 4;                    // rows per k4 block (R12-proven best)

typedef float f4v __attribute__((ext_vector_type(4)));

// ---------------------------------------------------------------------------
// K0: per-batch compaction of context-row indices from target_mask.
// dtype sniff: int32 vs int64 storage; odd-word nonzero => int32
// (int64 high words all zero; P[false int64] = 2^-256).
// ---------------------------------------------------------------------------
__global__ __launch_bounds__(256) void k0_compact(const int* __restrict__ m32,
                                                  int* __restrict__ rowlist,
                                                  int* __restrict__ cnt,
                                                  int* __restrict__ ntgt) {
    const int b    = blockIdx.x;
    const int t    = threadIdx.x;
    const int wave = t >> 6, lane = t & 63;

    const int probe = m32[(size_t)b * 2048 + 8 * t + 1];
    __shared__ unsigned long long pbw[4];
    const unsigned long long pb = __ballot(probe != 0);
    if (lane == 0) pbw[wave] = pb;
    __syncthreads();
    const int stride = ((pbw[0] | pbw[1] | pbw[2] | pbw[3]) != 0ull) ? 1 : 2;

    const int base = t * 8;
    int f[8];
    int ls = 0;
    #pragma unroll
    for (int k = 0; k < 8; ++k) {
        f[k] = (m32[((size_t)b * 2048 + base + k) * (size_t)stride] == 0) ? 1 : 0;
        ls += f[k];
    }

    int v = ls;
    #pragma unroll
    for (int o = 1; o < 64; o <<= 1) {
        const int u = __shfl_up(v, o, 64);
        if (lane >= o) v += u;
    }
    __shared__ int wsum[4];
    if (lane == 63) wsum[wave] = v;
    __syncthreads();
    int wbase = 0;
    for (int w = 0; w < wave; ++w) wbase += wsum[w];
    const int excl = wbase + v - ls;

    int c = 0;
    #pragma unroll
    for (int k = 0; k < 8; ++k) {
        if (f[k]) { rowlist[(size_t)b * 2048 + excl + c] = base + k; ++c; }
    }
    if (t == 0) {
        const int tot = wsum[0] + wsum[1] + wsum[2] + wsum[3];
        cnt[b]  = tot;
        ntgt[b] = LSEQ - tot;
    }
}

// ---------------------------------------------------------------------------
// K1: gather-sum over context rows only (~50% of x never read).
// Probe-verified at floor: ~18 us for the mandatory 128 MB.
// ---------------------------------------------------------------------------
__global__ __launch_bounds__(256) void k1_gather(const float* __restrict__ x,
                                                 const int* __restrict__ rowlist,
                                                 const int* __restrict__ cnt,
                                                 float* __restrict__ psum) {
    const int chunk = blockIdx.x;
    const int b     = blockIdx.y;
    const int t     = threadIdx.x;

    const int cntb = cnt[b];
    const int nch  = (cntb + 31) >> 5;
    if (chunk >= nch) return;
    const int rbeg = chunk * 32;
    const int rcnt = min(32, cntb - rbeg);

    __shared__ int sidx[32];
    if (t < rcnt) sidx[t] = rowlist[(size_t)b * 2048 + rbeg + t];
    __syncthreads();

    const float* xb = x + (size_t)b * LSEQ * DIM + t * 4;
    float4 acc = make_float4(0.f, 0.f, 0.f, 0.f);

    if (rcnt == 32) {                         // fast path: unconditional
        #pragma unroll 8
        for (int r = 0; r < 32; ++r) {
            const float4 v = *(const float4*)(xb + (size_t)sidx[r] * DIM);
            acc.x += v.x; acc.y += v.y; acc.z += v.z; acc.w += v.w;
        }
    } else {                                  // one partial chunk per batch
        for (int r = 0; r < rcnt; ++r) {
            const float4 v = *(const float4*)(xb + (size_t)sidx[r] * DIM);
            acc.x += v.x; acc.y += v.y; acc.z += v.z; acc.w += v.w;
        }
    }

    *(float4*)(psum + ((size_t)b * CHUNKS + chunk) * DIM + t * 4) = acc;
}

// ---------------------------------------------------------------------------
// K2: mean[b][d] = (sum over ceil(cnt/32) psum chunks) / max(cnt,1).
// One-shot 4 MB reduction; fusing it into k3a was measured slower (R9/R13).
// ---------------------------------------------------------------------------
__global__ __launch_bounds__(256) void k2_mean(const float* __restrict__ psum,
                                               const int* __restrict__ cnt,
                                               float* __restrict__ mean) {
    const int b = blockIdx.x;
    const int t = threadIdx.x;
    const int cntb = cnt[b];
    const int nch  = (cntb + 31) >> 5;

    float4 s = make_float4(0.f, 0.f, 0.f, 0.f);
    for (int c = 0; c < nch; ++c) {
        const float4 v = *(const float4*)(psum + ((size_t)b * CHUNKS + c) * DIM + t * 4);
        s.x += v.x; s.y += v.y; s.z += v.z; s.w += v.w;
    }
    const float denom = (float)(cntb > 1 ? cntb : 1);
    float4 m4;
    m4.x = s.x / denom; m4.y = s.y / denom; m4.z = s.z / denom; m4.w = s.w / denom;
    *(float4*)(mean + (size_t)b * DIM + t * 4) = m4;
}

// ---------------------------------------------------------------------------
// K3a: p1[ks][b][j] = mean[b, k-seg] @ W1[k-seg, j]. All 32 batches per block
// so W1 is read exactly once total (8 MB).
// ---------------------------------------------------------------------------
__global__ __launch_bounds__(256) void k3a_h(const float* __restrict__ mean,
                                             const float* __restrict__ W1,
                                             float* __restrict__ p1) {
    const int j  = blockIdx.x * 256 + threadIdx.x;
    const int ks = blockIdx.y;
    const int k0 = ks * KSEG1;

    __shared__ float mlds[BATCH][KSEG1];
    for (int i = threadIdx.x; i < BATCH * KSEG1; i += 256)
        mlds[i >> 5][i & 31] = mean[(size_t)(i >> 5) * DIM + k0 + (i & 31)];
    __syncthreads();

    float acc[BATCH];
    #pragma unroll
    for (int b = 0; b < BATCH; ++b) acc[b] = 0.f;

    #pragma unroll
    for (int k4 = 0; k4 < KSEG1 / 4; ++k4) {
        const float w0 = W1[(size_t)(k0 + 4 * k4 + 0) * DIM2 + j];
        const float w1 = W1[(size_t)(k0 + 4 * k4 + 1) * DIM2 + j];
        const float w2 = W1[(size_t)(k0 + 4 * k4 + 2) * DIM2 + j];
        const float w3 = W1[(size_t)(k0 + 4 * k4 + 3) * DIM2 + j];
        #pragma unroll
        for (int b = 0; b < BATCH; ++b) {
            const float4 m4 = *(const float4*)&mlds[b][k4 * 4];
            acc[b] += m4.x * w0; acc[b] += m4.y * w1;
            acc[b] += m4.z * w2; acc[b] += m4.w * w3;
        }
    }
    #pragma unroll
    for (int b = 0; b < BATCH; ++b)
        p1[((size_t)ks * BATCH + b) * DIM2 + j] = acc[b];
}

__device__ __forceinline__ float gelu_erf(float v) {
    return 0.5f * v * (1.f + erff(v * 0.70710678118654752f));
}

__device__ __forceinline__ float wave_sum(float v) {
    #pragma unroll
    for (int o = 32; o > 0; o >>= 1) v += __shfl_down(v, o, 64);
    return v;
}

// ---------------------------------------------------------------------------
// K3b (float4): h = sum(p1)+b1; gelu(erf); LayerNorm -> hn.
// ---------------------------------------------------------------------------
__global__ __launch_bounds__(256) void k3b_ln(const float* __restrict__ p1,
                                              const float* __restrict__ b1,
                                              const float* __restrict__ gamma,
                                              const float* __restrict__ beta,
                                              float* __restrict__ hn) {
    const int b = blockIdx.x;
    const int t = threadIdx.x;
    const int wave = t >> 6, lane = t & 63;
    __shared__ float red[4];

    float4 g[2];
    float ls = 0.f;
    #pragma unroll
    for (int i = 0; i < 2; ++i) {
        const int j = t * 4 + i * 1024;
        float4 s = *(const float4*)(b1 + j);
        #pragma unroll 8
        for (int ks = 0; ks < NSEG1; ++ks) {
            const float4 v = *(const float4*)(p1 + ((size_t)ks * BATCH + b) * DIM2 + j);
            s.x += v.x; s.y += v.y; s.z += v.z; s.w += v.w;
        }
        g[i].x = gelu_erf(s.x); g[i].y = gelu_erf(s.y);
        g[i].z = gelu_erf(s.z); g[i].w = gelu_erf(s.w);
        ls += g[i].x + g[i].y + g[i].z + g[i].w;
    }

    float w = wave_sum(ls);
    if (lane == 0) red[wave] = w;
    __syncthreads();
    const float mu = (red[0] + red[1] + red[2] + red[3]) * (1.f / (float)DIM2);
    __syncthreads();

    float lv = 0.f;
    #pragma unroll
    for (int i = 0; i < 2; ++i) {
        float d;
        d = g[i].x - mu; lv += d * d;
        d = g[i].y - mu; lv += d * d;
        d = g[i].z - mu; lv += d * d;
        d = g[i].w - mu; lv += d * d;
    }
    w = wave_sum(lv);
    if (lane == 0) red[wave] = w;
    __syncthreads();
    const float var = (red[0] + red[1] + red[2] + red[3]) * (1.f / (float)DIM2);
    const float rs = rsqrtf(var + EPSF);

    #pragma unroll
    for (int i = 0; i < 2; ++i) {
        const int j = t * 4 + i * 1024;
        const float4 ga = *(const float4*)(gamma + j);
        const float4 be = *(const float4*)(beta + j);
        float4 o;
        o.x = (g[i].x - mu) * rs * ga.x + be.x;
        o.y = (g[i].y - mu) * rs * ga.y + be.y;
        o.z = (g[i].z - mu) * rs * ga.z + be.z;
        o.w = (g[i].w - mu) * rs * ga.w + be.w;
        *(float4*)(hn + (size_t)b * DIM2 + j) = o;
    }
}

// ---------------------------------------------------------------------------
// K3c: p2[ks][b][j] = hn[b, k-seg] @ W2[k-seg, j]. W2 read exactly once.
// ---------------------------------------------------------------------------
__global__ __launch_bounds__(256) void k3c_o(const float* __restrict__ hn,
                                             const float* __restrict__ W2,
                                             float* __restrict__ p2) {
    const int j  = blockIdx.x * 256 + threadIdx.x;
    const int ks = blockIdx.y;
    const int k0 = ks * KSEG2;

    __shared__ float hl[BATCH][KSEG2];
    for (int i = threadIdx.x; i < BATCH * KSEG2; i += 256)
        hl[i >> 5][i & 31] = hn[(size_t)(i >> 5) * DIM2 + k0 + (i & 31)];
    __syncthreads();

    float acc[BATCH];
    #pragma unroll
    for (int b = 0; b < BATCH; ++b) acc[b] = 0.f;

    #pragma unroll
    for (int k4 = 0; k4 < KSEG2 / 4; ++k4) {
        const float w0 = W2[(size_t)(k0 + 4 * k4 + 0) * DIM + j];
        const float w1 = W2[(size_t)(k0 + 4 * k4 + 1) * DIM + j];
        const float w2 = W2[(size_t)(k0 + 4 * k4 + 2) * DIM + j];
        const float w3 = W2[(size_t)(k0 + 4 * k4 + 3) * DIM + j];
        #pragma unroll
        for (int b = 0; b < BATCH; ++b) {
            const float4 h4 = *(const float4*)&hl[b][k4 * 4];
            acc[b] += h4.x * w0; acc[b] += h4.y * w1;
            acc[b] += h4.z * w2; acc[b] += h4.w * w3;
        }
    }
    #pragma unroll
    for (int b = 0; b < BATCH; ++b)
        p2[((size_t)ks * BATCH + b) * DIM + j] = acc[b];
}

// ---------------------------------------------------------------------------
// K3d (float4): pred[b][j] = sum_ks p2[ks][b][j] + b2[j].
// ---------------------------------------------------------------------------
__global__ __launch_bounds__(256) void k3d_pred(const float* __restrict__ p2,
                                                const float* __restrict__ b2,
                                                float* __restrict__ pred) {
    const int b = blockIdx.x;
    const int j = threadIdx.x * 4;
    float4 s = *(const float4*)(b2 + j);
    #pragma unroll 8
    for (int ks = 0; ks < NSEG2; ++ks) {
        const float4 v = *(const float4*)(p2 + ((size_t)ks * BATCH + b) * DIM + j);
        s.x += v.x; s.y += v.y; s.z += v.z; s.w += v.w;
    }
    *(float4*)(pred + (size_t)b * DIM + j) = s;
}

// ---------------------------------------------------------------------------
// K4: 4 rows per block, nontemporal stores — both A/B-verified best:
// 4-row vs thin = -7 us (R12 vs R8); nt vs plain = -12 us (R12 vs R14:
// plain's 140 MB of L2/L3 pollution cools x/psum across graph replays).
// ---------------------------------------------------------------------------
__global__ __launch_bounds__(256) void k4_scatter(const float* __restrict__ pred,
                                                  const int* __restrict__ ntgt,
                                                  f4v* __restrict__ out,
                                                  int T) {
    const int b  = blockIdx.y;
    const int t0 = blockIdx.x * K4_ROWS;
    const int d4 = threadIdx.x;
    const int n  = ntgt[b];

    const f4v p = ((const f4v*)pred)[b * 256 + d4];
    const f4v z = (f4v)(0.f);

    f4v* o = out + ((size_t)b * T + t0) * 256 + d4;
    #pragma unroll
    for (int r = 0; r < K4_ROWS; ++r) {
        const int tt = t0 + r;
        if (tt >= T) break;                   // block-uniform
        __builtin_nontemporal_store((tt < n) ? p : z, &o[(size_t)r * 256]);
    }
}

// ---------------------------------------------------------------------------
extern "C" void kernel_launch(void* const* d_in, const int* in_sizes, int n_in,
                              void* d_out, int out_size, void* d_ws, size_t ws_size,
                              hipStream_t stream) {
    const float* x     = (const float*)d_in[0];
    const int*   mask  = (const int*)d_in[1];   // int32 or int64 storage — sniffed in k0
    const float* W1    = (const float*)d_in[2];
    const float* b1    = (const float*)d_in[3];
    const float* gamma = (const float*)d_in[4];
    const float* beta  = (const float*)d_in[5];
    const float* W2    = (const float*)d_in[6];
    const float* b2    = (const float*)d_in[7];

    char* ws = (char*)d_ws;
    float* psum = (float*)(ws);                                   // 8 MB (alias p2)
    float* p2   = psum;                                           // psum dead after k2
    float* p1   = (float*)(ws + (8u  << 20));                     // 8 MB
    float* mean = (float*)(ws + (16u << 20));                     // 128 KB
    float* hn   = (float*)(ws + (16u << 20) + (128u << 10));      // 256 KB
    float* pred = (float*)(ws + (16u << 20) + (384u << 10));      // 128 KB
    int* rowlist= (int*)  (ws + (17u << 20));                     // 256 KB
    int*   cnt  = rowlist + BATCH * LSEQ;
    int*   ntgt = cnt + 64;

    const int T = out_size / (BATCH * DIM);   // num_targets, from output shape

    k0_compact<<<BATCH, 256, 0, stream>>>(mask, rowlist, cnt, ntgt);
    k1_gather<<<dim3(CHUNKS, BATCH), 256, 0, stream>>>(x, rowlist, cnt, psum);
    k2_mean  <<<BATCH, 256, 0, stream>>>(psum, cnt, mean);
    k3a_h    <<<dim3(DIM2 / 256, NSEG1), 256, 0, stream>>>(mean, W1, p1);
    k3b_ln   <<<BATCH, 256, 0, stream>>>(p1, b1, gamma, beta, hn);
    k3c_o    <<<dim3(DIM / 256, NSEG2), 256, 0, stream>>>(hn, W2, p2);
    k3d_pred <<<BATCH, 256, 0, stream>>>(p2, b2, pred);
    k4_scatter<<<dim3((T + K4_ROWS - 1) / K4_ROWS, BATCH), 256, 0, stream>>>(pred, ntgt, (f4v*)d_out, T);
}